// Round 14
// baseline (1128.347 us; speedup 1.0000x reference)
//
#include <hip/hip_runtime.h>

// B=4096, T=512, IN=32, H=[64,64,128], OUT=10
// 256 blocks x 1024 threads (16 waves, 4 waves/SIMD). 2-deep-skew pipeline with ONE
// barrier per step:
//   iteration t:  L0 (waves 0-3):  layer0(t)
//                 L1 (waves 4-7):  layer1(t-1)
//                 L2 (waves 8-15): layer2(t-2)
//                 __syncthreads()
// Wave->SIMD round-robin gives each SIMD 1xL0 + 1xL1 + 2xL2 = 160 trans-instr/step
// (trans pipe floor: 160 x 16 cyc = 2560 cyc/step); 4 waves/SIMD hide MFMA/LDS/
// barrier stalls under trans issue, and the single barrier removes one full drain.
// Race audit (pb=t&1, rb=pb^1; each h array double-buffered by ITS step parity):
//   L0 writes h0s[pb]=h0(t),   reads h0s[rb]=h0(t-1)            (opposite buffers)
//   L1 writes h1s[rb]=h1(t-1), reads h0s[rb]=h0(t-1) (prev iter, barrier-crossed),
//                              reads h1s[pb]=h1(t-2)            (opposite buffer)
//   L2 writes h2s[pb]=h2(t-2), reads h1s[pb]=h1(t-2) (prev iter, barrier-crossed),
//                              reads h2s[rb]=h2(t-3)            (opposite buffer)
// Weights: union WS[16] PINNED to AGPRs (64 AGPR/wave; R11 mechanism -> escapes the
// 64-arch-VGPR budget the compiler imposes at 1024-thread blocks, which is what
// killed R10). L0: [3gi+0]=Wih0,[3gi+1..2]=Whh0; L1: [4gi+0..1]=Wih1,[4gi+2..3]=Whh1;
// L2: [4gi+kk]=Whh2; Wih2 read from LDS. Working sets ~50-60 arch regs < 64.
// Biases pre-scaled into exp2 args (R12); native bf16 casts; builtin MFMAs only.

using f32x4  = __attribute__((ext_vector_type(4))) float;
using bf16x8 = __attribute__((ext_vector_type(8))) __bf16;

#define KS (-1.442695041f)   // -log2(e)
#define KT (-2.885390082f)   // -2*log2(e)

__device__ __forceinline__ float bf2f(__bf16 b) {
  unsigned short s = __builtin_bit_cast(unsigned short, b);
  unsigned u = ((unsigned)s) << 16;
  return __builtin_bit_cast(float, u);
}
__device__ __forceinline__ float sig_u(float u) {   // sigmoid, u = KS*(x+b)
  return __builtin_amdgcn_rcpf(1.0f + __builtin_amdgcn_exp2f(u));
}
__device__ __forceinline__ float tanh_u(float u) {  // tanh, u = KT*(x+b)
  return 2.0f * __builtin_amdgcn_rcpf(1.0f + __builtin_amdgcn_exp2f(u)) - 1.0f;
}

#define MF(A, Bv, C) __builtin_amdgcn_mfma_f32_16x16x32_bf16((A), (Bv), (C), 0, 0, 0)
#define PIN_A(v) asm volatile("" : "+a"(v))

__device__ __forceinline__ bf16x8 ldw8(const float* p) {
  float4 v0 = *(const float4*)p;
  float4 v1 = *(const float4*)(p + 4);
  bf16x8 r;
  r[0] = (__bf16)v0.x; r[1] = (__bf16)v0.y; r[2] = (__bf16)v0.z; r[3] = (__bf16)v0.w;
  r[4] = (__bf16)v1.x; r[5] = (__bf16)v1.y; r[6] = (__bf16)v1.z; r[7] = (__bf16)v1.w;
  return r;
}

__global__ __launch_bounds__(1024)
void lstm_kernel(const float* __restrict__ x,
                 const float* __restrict__ Wih0, const float* __restrict__ Whh0,
                 const float* __restrict__ bih0, const float* __restrict__ bhh0,
                 const float* __restrict__ Wih1, const float* __restrict__ Whh1,
                 const float* __restrict__ bih1, const float* __restrict__ bhh1,
                 const float* __restrict__ Wih2, const float* __restrict__ Whh2,
                 const float* __restrict__ bih2, const float* __restrict__ bhh2,
                 const float* __restrict__ Wfc, const float* __restrict__ bfc,
                 float* __restrict__ out) {
  __shared__ __align__(16) __bf16 h0s[2][16][72];
  __shared__ __align__(16) __bf16 h1s[2][16][72];
  __shared__ __align__(16) __bf16 h2s[2][16][136];
  __shared__ __align__(16) __bf16 wih2l[512][72];

  const int tid  = threadIdx.x;
  const int w    = tid >> 6;                        // wave 0..15
  const int role = (w < 4) ? 0 : (w < 8 ? 1 : 2);   // 4 L0, 4 L1, 8 L2
  const int sc   = w - ((role == 0) ? 0 : (role == 1) ? 4 : 8);
  const int l    = tid & 63;
  const int l15  = l & 15;
  const int lg   = l >> 4;
  const int k0   = lg * 8;
  const int r0   = blockIdx.x << 4;

  for (int i = tid; i < 2 * 16 * 72; i += 1024) {
    (&h0s[0][0][0])[i] = __bf16(0.f);
    (&h1s[0][0][0])[i] = __bf16(0.f);
  }
  for (int i = tid; i < 2 * 16 * 136; i += 1024) (&h2s[0][0][0])[i] = __bf16(0.f);
  for (int i = tid; i < 512 * 64; i += 1024) {
    int row = i >> 6, col = i & 63;
    wih2l[row][col] = (__bf16)Wih2[i];
  }

  // ---- union weight array, pinned to AGPRs (64 AGPRs/wave) ----
  bf16x8 WS[16];
#pragma unroll
  for (int i = 0; i < 16; ++i) WS[i] = bf16x8{};
  float BI[4];     // pre-scaled biases (gi==2 -> KT*b else KS*b)
  float CS[4];     // cell states (4 batch rows per thread, this unit column)
#pragma unroll
  for (int i = 0; i < 4; ++i) CS[i] = 0.f;

  if (role == 0) {
#pragma unroll
    for (int gi = 0; gi < 4; ++gi) {
      const int row = 16 * (4 * gi + sc) + l15;
      WS[3 * gi + 0] = ldw8(Wih0 + (size_t)row * 32 + k0);
      WS[3 * gi + 1] = ldw8(Whh0 + (size_t)row * 64 + k0);
      WS[3 * gi + 2] = ldw8(Whh0 + (size_t)row * 64 + 32 + k0);
      const float scale = (gi == 2) ? KT : KS;
      const int c = 64 * gi + 16 * sc + l15;
      BI[gi] = scale * (bih0[c] + bhh0[c]);
    }
  } else if (role == 1) {
#pragma unroll
    for (int gi = 0; gi < 4; ++gi) {
      const int row = 16 * (4 * gi + sc) + l15;
      WS[4 * gi + 0] = ldw8(Wih1 + (size_t)row * 64 + k0);
      WS[4 * gi + 1] = ldw8(Wih1 + (size_t)row * 64 + 32 + k0);
      WS[4 * gi + 2] = ldw8(Whh1 + (size_t)row * 64 + k0);
      WS[4 * gi + 3] = ldw8(Whh1 + (size_t)row * 64 + 32 + k0);
      const float scale = (gi == 2) ? KT : KS;
      const int c = 64 * gi + 16 * sc + l15;
      BI[gi] = scale * (bih1[c] + bhh1[c]);
    }
  } else {
#pragma unroll
    for (int gi = 0; gi < 4; ++gi) {
      const int row = 16 * (8 * gi + sc) + l15;
#pragma unroll
      for (int kk = 0; kk < 4; ++kk)
        WS[4 * gi + kk] = ldw8(Whh2 + (size_t)row * 128 + kk * 32 + k0);
      const float scale = (gi == 2) ? KT : KS;
      const int c = 128 * gi + 16 * sc + l15;
      BI[gi] = scale * (bih2[c] + bhh2[c]);
    }
  }
#pragma unroll
  for (int i = 0; i < 16; ++i) PIN_A(WS[i]);

  // x prefetch (L0 waves only; all 4 L0 waves load the same rows -> cached)
  const float* xrow = x + (size_t)(r0 + l15) * 512 * 32 + k0;
  float4 nx0 = {0.f, 0.f, 0.f, 0.f}, nx1 = {0.f, 0.f, 0.f, 0.f};
  if (role == 0) { nx0 = *(const float4*)xrow; nx1 = *(const float4*)(xrow + 4); }

  const f32x4 Z0 = {0.f, 0.f, 0.f, 0.f};

  __syncthreads();

#pragma unroll 1
  for (int t = 0; t <= 513; ++t) {
    const int pb = t & 1, rb = pb ^ 1;

    if (role == 0) {
      if (t < 512) {
        // -------- layer0(t): h0(t) = cell(x(t), h0(t-1)) --------
        float4 cx0 = nx0, cx1 = nx1;
        const int tn = (t + 1) & 511;  // wraparound dummy at t=511
        nx0 = *(const float4*)(xrow + (size_t)tn * 32);
        nx1 = *(const float4*)(xrow + (size_t)tn * 32 + 4);

        bf16x8 ax;
        ax[0] = (__bf16)cx0.x; ax[1] = (__bf16)cx0.y; ax[2] = (__bf16)cx0.z; ax[3] = (__bf16)cx0.w;
        ax[4] = (__bf16)cx1.x; ax[5] = (__bf16)cx1.y; ax[6] = (__bf16)cx1.z; ax[7] = (__bf16)cx1.w;

        bf16x8 a0 = *(const bf16x8*)&h0s[rb][l15][k0];
        bf16x8 a1 = *(const bf16x8*)&h0s[rb][l15][32 + k0];

        f32x4 A0 = Z0, A1 = Z0, A2 = Z0, A3 = Z0;
        A0 = MF(ax, WS[0], A0);  A0 = MF(a0, WS[1],  A0);  A0 = MF(a1, WS[2],  A0);
        A1 = MF(ax, WS[3], A1);  A1 = MF(a0, WS[4],  A1);  A1 = MF(a1, WS[5],  A1);
        A2 = MF(ax, WS[6], A2);  A2 = MF(a0, WS[7],  A2);  A2 = MF(a1, WS[8],  A2);
        A3 = MF(ax, WS[9], A3);  A3 = MF(a0, WS[10], A3);  A3 = MF(a1, WS[11], A3);
#pragma unroll
        for (int j = 0; j < 4; ++j) {
          float si = sig_u (fmaf(KS, A0[j], BI[0]));
          float sf = sig_u (fmaf(KS, A1[j], BI[1]));
          float tg = tanh_u(fmaf(KT, A2[j], BI[2]));
          float so = sig_u (fmaf(KS, A3[j], BI[3]));
          float nc = sf * CS[j] + si * tg;
          CS[j] = nc;
          h0s[pb][4 * lg + j][16 * sc + l15] = (__bf16)(so * tanh_u(KT * nc));
        }
      }
    } else if (role == 1) {
      if (t >= 1 && t <= 512) {
        // -------- layer1(t-1): h1(t-1) = cell(h0(t-1), h1(t-2)) --------
        bf16x8 a0 = *(const bf16x8*)&h0s[rb][l15][k0];
        bf16x8 a1 = *(const bf16x8*)&h0s[rb][l15][32 + k0];
        bf16x8 b0 = *(const bf16x8*)&h1s[pb][l15][k0];
        bf16x8 b1 = *(const bf16x8*)&h1s[pb][l15][32 + k0];

        f32x4 A0 = Z0, A1 = Z0, A2 = Z0, A3 = Z0;
        A0 = MF(a0, WS[0],  A0); A0 = MF(a1, WS[1],  A0); A0 = MF(b0, WS[2],  A0); A0 = MF(b1, WS[3],  A0);
        A1 = MF(a0, WS[4],  A1); A1 = MF(a1, WS[5],  A1); A1 = MF(b0, WS[6],  A1); A1 = MF(b1, WS[7],  A1);
        A2 = MF(a0, WS[8],  A2); A2 = MF(a1, WS[9],  A2); A2 = MF(b0, WS[10], A2); A2 = MF(b1, WS[11], A2);
        A3 = MF(a0, WS[12], A3); A3 = MF(a1, WS[13], A3); A3 = MF(b0, WS[14], A3); A3 = MF(b1, WS[15], A3);
#pragma unroll
        for (int j = 0; j < 4; ++j) {
          float si = sig_u (fmaf(KS, A0[j], BI[0]));
          float sf = sig_u (fmaf(KS, A1[j], BI[1]));
          float tg = tanh_u(fmaf(KT, A2[j], BI[2]));
          float so = sig_u (fmaf(KS, A3[j], BI[3]));
          float nc = sf * CS[j] + si * tg;
          CS[j] = nc;
          h1s[rb][4 * lg + j][16 * sc + l15] = (__bf16)(so * tanh_u(KT * nc));
        }
      }
    } else {
      if (t >= 2) {
        // -------- layer2(t-2): h2(t-2) = cell(h1(t-2), h2(t-3)) --------
        bf16x8 b0 = *(const bf16x8*)&h1s[pb][l15][k0];
        bf16x8 b1 = *(const bf16x8*)&h1s[pb][l15][32 + k0];
        bf16x8 d0 = *(const bf16x8*)&h2s[rb][l15][k0];
        bf16x8 d1 = *(const bf16x8*)&h2s[rb][l15][32 + k0];
        bf16x8 d2 = *(const bf16x8*)&h2s[rb][l15][64 + k0];
        bf16x8 d3 = *(const bf16x8*)&h2s[rb][l15][96 + k0];

        f32x4 A0 = Z0, A1 = Z0, A2 = Z0, A3 = Z0;
        {
          bf16x8 wa0 = *(const bf16x8*)&wih2l[16 * (0 + sc) + l15][k0];
          bf16x8 wa1 = *(const bf16x8*)&wih2l[16 * (0 + sc) + l15][32 + k0];
          A0 = MF(b0, wa0, A0); A0 = MF(b1, wa1, A0);
          A0 = MF(d0, WS[0], A0); A0 = MF(d1, WS[1], A0); A0 = MF(d2, WS[2], A0); A0 = MF(d3, WS[3], A0);
        }
        {
          bf16x8 wa0 = *(const bf16x8*)&wih2l[16 * (8 + sc) + l15][k0];
          bf16x8 wa1 = *(const bf16x8*)&wih2l[16 * (8 + sc) + l15][32 + k0];
          A1 = MF(b0, wa0, A1); A1 = MF(b1, wa1, A1);
          A1 = MF(d0, WS[4], A1); A1 = MF(d1, WS[5], A1); A1 = MF(d2, WS[6], A1); A1 = MF(d3, WS[7], A1);
        }
        {
          bf16x8 wa0 = *(const bf16x8*)&wih2l[16 * (16 + sc) + l15][k0];
          bf16x8 wa1 = *(const bf16x8*)&wih2l[16 * (16 + sc) + l15][32 + k0];
          A2 = MF(b0, wa0, A2); A2 = MF(b1, wa1, A2);
          A2 = MF(d0, WS[8], A2); A2 = MF(d1, WS[9], A2); A2 = MF(d2, WS[10], A2); A2 = MF(d3, WS[11], A2);
        }
        {
          bf16x8 wa0 = *(const bf16x8*)&wih2l[16 * (24 + sc) + l15][k0];
          bf16x8 wa1 = *(const bf16x8*)&wih2l[16 * (24 + sc) + l15][32 + k0];
          A3 = MF(b0, wa0, A3); A3 = MF(b1, wa1, A3);
          A3 = MF(d0, WS[12], A3); A3 = MF(d1, WS[13], A3); A3 = MF(d2, WS[14], A3); A3 = MF(d3, WS[15], A3);
        }
#pragma unroll
        for (int j = 0; j < 4; ++j) {
          float si = sig_u (fmaf(KS, A0[j], BI[0]));
          float sf = sig_u (fmaf(KS, A1[j], BI[1]));
          float tg = tanh_u(fmaf(KT, A2[j], BI[2]));
          float so = sig_u (fmaf(KS, A3[j], BI[3]));
          float nc = sf * CS[j] + si * tg;
          CS[j] = nc;
          h2s[pb][4 * lg + j][16 * sc + l15] = (__bf16)(so * tanh_u(KT * nc));
        }
      }
    }
    __syncthreads();
  }

  // ---- final FC: out = h2(511) @ Wfc^T + bfc; h2(511) written at t=513 -> h2s[1]
  if (tid < 160) {
    const int r = tid / 10, o = tid - r * 10;
    float sum = bfc[o];
    for (int u = 0; u < 128; ++u) sum += bf2f(h2s[1][r][u]) * Wfc[o * 128 + u];
    out[(size_t)(r0 + r) * 10 + o] = sum;
  }
}

extern "C" void kernel_launch(void* const* d_in, const int* in_sizes, int n_in,
                              void* d_out, int out_size, void* d_ws, size_t ws_size,
                              hipStream_t stream) {
  const float* x    = (const float*)d_in[0];
  const float* Wih0 = (const float*)d_in[1];
  const float* Whh0 = (const float*)d_in[2];
  const float* bih0 = (const float*)d_in[3];
  const float* bhh0 = (const float*)d_in[4];
  const float* Wih1 = (const float*)d_in[5];
  const float* Whh1 = (const float*)d_in[6];
  const float* bih1 = (const float*)d_in[7];
  const float* bhh1 = (const float*)d_in[8];
  const float* Wih2 = (const float*)d_in[9];
  const float* Whh2 = (const float*)d_in[10];
  const float* bih2 = (const float*)d_in[11];
  const float* bhh2 = (const float*)d_in[12];
  const float* Wfc  = (const float*)d_in[13];
  const float* bfc  = (const float*)d_in[14];

  lstm_kernel<<<256, 1024, 0, stream>>>(x, Wih0, Whh0, bih0, bhh0,
                                        Wih1, Whh1, bih1, bhh1,
                                        Wih2, Whh2, bih2, bhh2,
                                        Wfc, bfc, (float*)d_out);
}

// Round 15
// 909.169 us; speedup vs baseline: 1.2411x; 1.2411x over previous
//
#include <hip/hip_runtime.h>

// B=4096, T=512, IN=32, H=[64,64,128], OUT=10
// 256 blocks x 512 threads (8 waves, 2/SIMD). Wave-specialized pipeline (=R13):
//   slot1: G01 (waves 0-3): layer0(t) MFMA+acts
//          G23 (waves 4-7): layer2(t-1) s=0 MFMA -> s=0 acts+write -> s=1 MFMA
//   B1
//   slot2: G01: layer1(t) MFMA+acts;   G23: s=1 acts+write
//   B2
// R15: trans-count reduction. The kernel is transcendental-issue-bound
// (VALU-busy ~2960 cyc/step ~= 160 trans x 16cyc + ~220 VALU x 2). Old cell math:
// 5 exp2 + 5 rcp. New: common-denominator fractions ->
//   nc = [c*Pi*Pg + Pf*(1-Eg)] * rcp(Pf*Pi*Pg)      (1 rcp for 3)
//   h  = (1-En) * rcp(Po*(1+En)), En = exp2(KT*nc)  (1 rcp for 2)
// = 5 exp2 + 2 rcp + ~5 extra cheap VALU. Overflow-safe for this data (|gate|<~3).
// Weights in AGPRs (PIN_A union AG[32], R11); biases pre-scaled (R12); native bf16
// casts; builtin MFMAs only (compiler-managed hazards).

using f32x4  = __attribute__((ext_vector_type(4))) float;
using bf16x8 = __attribute__((ext_vector_type(8))) __bf16;

#define KS (-1.442695041f)   // -log2(e)
#define KT (-2.885390082f)   // -2*log2(e)

__device__ __forceinline__ float bf2f(__bf16 b) {
  unsigned short s = __builtin_bit_cast(unsigned short, b);
  unsigned u = ((unsigned)s) << 16;
  return __builtin_bit_cast(float, u);
}

// Full LSTM cell pointwise math, 7 trans ops (5 exp2 + 2 rcp).
// ai/af/ag/ao: raw gate accumulators; bi*: PRE-SCALED biases (KS*b or KT*b);
// cs: cell state in/out. Returns h.
__device__ __forceinline__ float lstm_h(float ai, float af, float ag, float ao,
                                        float bi0, float bi1, float bi2, float bi3,
                                        float& cs) {
  float Ei = __builtin_amdgcn_exp2f(fmaf(KS, ai, bi0));
  float Ef = __builtin_amdgcn_exp2f(fmaf(KS, af, bi1));
  float Eg = __builtin_amdgcn_exp2f(fmaf(KT, ag, bi2));
  float Eo = __builtin_amdgcn_exp2f(fmaf(KS, ao, bi3));
  float Pi = 1.0f + Ei, Pf = 1.0f + Ef, Pg = 1.0f + Eg, Po = 1.0f + Eo;
  float PiPg = Pi * Pg;
  float N    = fmaf(Pf, 1.0f - Eg, cs * PiPg);
  float nc   = N * __builtin_amdgcn_rcpf(Pf * PiPg);
  cs = nc;
  float En = __builtin_amdgcn_exp2f(KT * nc);
  return (1.0f - En) * __builtin_amdgcn_rcpf(fmaf(Po, En, Po));  // (1-En)/(Po*(1+En))
}

#define MF(A, Bv, C) __builtin_amdgcn_mfma_f32_16x16x32_bf16((A), (Bv), (C), 0, 0, 0)
#define PIN_A(v) asm volatile("" : "+a"(v))

__device__ __forceinline__ bf16x8 ldw8(const float* p) {
  float4 v0 = *(const float4*)p;
  float4 v1 = *(const float4*)(p + 4);
  bf16x8 r;
  r[0] = (__bf16)v0.x; r[1] = (__bf16)v0.y; r[2] = (__bf16)v0.z; r[3] = (__bf16)v0.w;
  r[4] = (__bf16)v1.x; r[5] = (__bf16)v1.y; r[6] = (__bf16)v1.z; r[7] = (__bf16)v1.w;
  return r;
}

__global__ __launch_bounds__(512)
void lstm_kernel(const float* __restrict__ x,
                 const float* __restrict__ Wih0, const float* __restrict__ Whh0,
                 const float* __restrict__ bih0, const float* __restrict__ bhh0,
                 const float* __restrict__ Wih1, const float* __restrict__ Whh1,
                 const float* __restrict__ bih1, const float* __restrict__ bhh1,
                 const float* __restrict__ Wih2, const float* __restrict__ Whh2,
                 const float* __restrict__ bih2, const float* __restrict__ bhh2,
                 const float* __restrict__ Wfc, const float* __restrict__ bfc,
                 float* __restrict__ out) {
  __shared__ __align__(16) __bf16 h0s[2][16][72];
  __shared__ __align__(16) __bf16 h1s[2][16][72];
  __shared__ __align__(16) __bf16 h2s[2][16][136];
  __shared__ __align__(16) __bf16 wih2l[512][72];

  const int tid = threadIdx.x;
  const int w   = tid >> 6;      // wave 0..7
  const bool g01 = (w < 4);
  const int gw  = w & 3;
  const int l   = tid & 63;
  const int l15 = l & 15;
  const int lg  = l >> 4;
  const int k0  = lg * 8;
  const int r0  = blockIdx.x << 4;

  for (int i = tid; i < 2 * 16 * 72; i += 512) {
    (&h0s[0][0][0])[i] = __bf16(0.f);
    (&h1s[0][0][0])[i] = __bf16(0.f);
  }
  for (int i = tid; i < 2 * 16 * 136; i += 512) (&h2s[0][0][0])[i] = __bf16(0.f);
  for (int i = tid; i < 512 * 64; i += 512) {
    int row = i >> 6, col = i & 63;
    wih2l[row][col] = (__bf16)Wih2[i];
  }

  // ---- SHARED weight array (union across roles), pinned to AGPRs ----
  // G01: AG[0..3]=Wih0, AG[4..11]=Whh0, AG[12..19]=Wih1, AG[20..27]=Whh1
  // G23: AG[0..31]=Whh2 (s,gi,kk -> 16s+4gi+kk)
  bf16x8 AG[32];
#pragma unroll
  for (int i = 0; i < 32; ++i) AG[i] = bf16x8{};
  f32x4  AC[8];     // G01: AC[0..3] l0/l1; G23: AC[gi]=s0 (slot1-local), AC[4+gi]=s1 (across B1)
  float  BI[8];     // pre-scaled biases (gi==2 -> KT*b else KS*b)
  float  CS[8];     // cell states
#pragma unroll
  for (int i = 0; i < 8; ++i) CS[i] = 0.f;

  if (g01) {
#pragma unroll
    for (int gi = 0; gi < 4; ++gi) {
      const int row = 16 * (4 * gi + gw) + l15;
      AG[gi] = ldw8(Wih0 + (size_t)row * 32 + k0);
#pragma unroll
      for (int kb = 0; kb < 2; ++kb) {
        AG[4 + 2 * gi + kb]  = ldw8(Whh0 + (size_t)row * 64 + kb * 32 + k0);
        AG[12 + 2 * gi + kb] = ldw8(Wih1 + (size_t)row * 64 + kb * 32 + k0);
        AG[20 + 2 * gi + kb] = ldw8(Whh1 + (size_t)row * 64 + kb * 32 + k0);
      }
      const float sc = (gi == 2) ? KT : KS;
      const int c01 = 64 * gi + 16 * gw + l15;
      BI[gi]     = sc * (bih0[c01] + bhh0[c01]);
      BI[4 + gi] = sc * (bih1[c01] + bhh1[c01]);
    }
  } else {
#pragma unroll
    for (int s = 0; s < 2; ++s)
#pragma unroll
      for (int gi = 0; gi < 4; ++gi) {
        const int row = 16 * (8 * gi + 2 * gw + s) + l15;
#pragma unroll
        for (int kk = 0; kk < 4; ++kk)
          AG[16 * s + 4 * gi + kk] = ldw8(Whh2 + (size_t)row * 128 + kk * 32 + k0);
        const float sc = (gi == 2) ? KT : KS;
        const int c2 = 128 * gi + 32 * gw + 16 * s + l15;
        BI[4 * s + gi] = sc * (bih2[c2] + bhh2[c2]);
      }
  }
#pragma unroll
  for (int i = 0; i < 32; ++i) PIN_A(AG[i]);

  const float* xrow = x + (size_t)(r0 + l15) * 512 * 32 + k0;
  float4 nx0 = {0.f, 0.f, 0.f, 0.f}, nx1 = {0.f, 0.f, 0.f, 0.f};
  if (g01) { nx0 = *(const float4*)xrow; nx1 = *(const float4*)(xrow + 4); }

  const f32x4 Z0 = {0.f, 0.f, 0.f, 0.f};

  __syncthreads();

#pragma unroll 1
  for (int t = 0; t <= 512; ++t) {
    const int pb = t & 1, rb = pb ^ 1;

    // ---------------- slot 1 ----------------
    if (g01) {
      if (t < 512) {
        // layer0(t): h0(t) = cell(x(t), h0(t-1))
        float4 cx0 = nx0, cx1 = nx1;
        const int tn = (t + 1) & 511;
        nx0 = *(const float4*)(xrow + (size_t)tn * 32);
        nx1 = *(const float4*)(xrow + (size_t)tn * 32 + 4);

        bf16x8 ax;
        ax[0] = (__bf16)cx0.x; ax[1] = (__bf16)cx0.y; ax[2] = (__bf16)cx0.z; ax[3] = (__bf16)cx0.w;
        ax[4] = (__bf16)cx1.x; ax[5] = (__bf16)cx1.y; ax[6] = (__bf16)cx1.z; ax[7] = (__bf16)cx1.w;

        bf16x8 a0 = *(const bf16x8*)&h0s[rb][l15][k0];
        bf16x8 a1 = *(const bf16x8*)&h0s[rb][l15][32 + k0];
#pragma unroll
        for (int gi = 0; gi < 4; ++gi) {
          f32x4 a = Z0;
          a = MF(ax, AG[gi], a);
          a = MF(a0, AG[4 + 2 * gi], a);
          a = MF(a1, AG[5 + 2 * gi], a);
          AC[gi] = a;
        }
#pragma unroll
        for (int j = 0; j < 4; ++j) {
          float h = lstm_h(AC[0][j], AC[1][j], AC[2][j], AC[3][j],
                           BI[0], BI[1], BI[2], BI[3], CS[j]);
          h0s[pb][4 * lg + j][16 * gw + l15] = (__bf16)h;
        }
      }
    } else {
      if (t >= 1) {
        // layer2(t-1): s=0 MFMA -> s=0 acts + write -> s=1 MFMA
        bf16x8 b0 = *(const bf16x8*)&h1s[rb][l15][k0];
        bf16x8 b1 = *(const bf16x8*)&h1s[rb][l15][32 + k0];
        bf16x8 d0 = *(const bf16x8*)&h2s[pb][l15][k0];
        bf16x8 d1 = *(const bf16x8*)&h2s[pb][l15][32 + k0];
        bf16x8 d2 = *(const bf16x8*)&h2s[pb][l15][64 + k0];
        bf16x8 d3 = *(const bf16x8*)&h2s[pb][l15][96 + k0];
        // s = 0 MFMA chain
#pragma unroll
        for (int gi = 0; gi < 4; ++gi) {
          const int tile = 8 * gi + 2 * gw;
          bf16x8 wa0 = *(const bf16x8*)&wih2l[16 * tile + l15][k0];
          bf16x8 wa1 = *(const bf16x8*)&wih2l[16 * tile + l15][32 + k0];
          f32x4 a = Z0;
          a = MF(b0, wa0, a);
          a = MF(b1, wa1, a);
          a = MF(d0, AG[4 * gi + 0], a);
          a = MF(d1, AG[4 * gi + 1], a);
          a = MF(d2, AG[4 * gi + 2], a);
          a = MF(d3, AG[4 * gi + 3], a);
          AC[gi] = a;
        }
        // s = 0 activations + h2 write
#pragma unroll
        for (int j = 0; j < 4; ++j) {
          float h = lstm_h(AC[0][j], AC[1][j], AC[2][j], AC[3][j],
                           BI[0], BI[1], BI[2], BI[3], CS[j]);
          h2s[rb][4 * lg + j][32 * gw + l15] = (__bf16)h;
        }
        // s = 1 MFMA chain (accumulators live across B1)
#pragma unroll
        for (int gi = 0; gi < 4; ++gi) {
          const int tile = 8 * gi + 2 * gw + 1;
          bf16x8 wa0 = *(const bf16x8*)&wih2l[16 * tile + l15][k0];
          bf16x8 wa1 = *(const bf16x8*)&wih2l[16 * tile + l15][32 + k0];
          f32x4 a = Z0;
          a = MF(b0, wa0, a);
          a = MF(b1, wa1, a);
          a = MF(d0, AG[16 + 4 * gi + 0], a);
          a = MF(d1, AG[16 + 4 * gi + 1], a);
          a = MF(d2, AG[16 + 4 * gi + 2], a);
          a = MF(d3, AG[16 + 4 * gi + 3], a);
          AC[4 + gi] = a;
        }
      }
    }
    __syncthreads();  // B1: h0(t) visible to G01-l1

    // ---------------- slot 2 ----------------
    if (g01) {
      if (t < 512) {
        // layer1(t): h1(t) = cell(h0(t), h1(t-1))
        bf16x8 a0 = *(const bf16x8*)&h0s[pb][l15][k0];
        bf16x8 a1 = *(const bf16x8*)&h0s[pb][l15][32 + k0];
        bf16x8 b0 = *(const bf16x8*)&h1s[rb][l15][k0];
        bf16x8 b1 = *(const bf16x8*)&h1s[rb][l15][32 + k0];
#pragma unroll
        for (int gi = 0; gi < 4; ++gi) {
          f32x4 a = Z0;
          a = MF(a0, AG[12 + 2 * gi], a);
          a = MF(a1, AG[13 + 2 * gi], a);
          a = MF(b0, AG[20 + 2 * gi], a);
          a = MF(b1, AG[21 + 2 * gi], a);
          AC[gi] = a;
        }
#pragma unroll
        for (int j = 0; j < 4; ++j) {
          float h = lstm_h(AC[0][j], AC[1][j], AC[2][j], AC[3][j],
                           BI[4], BI[5], BI[6], BI[7], CS[4 + j]);
          h1s[pb][4 * lg + j][16 * gw + l15] = (__bf16)h;
        }
      }
    } else {
      if (t >= 1) {
        // layer2(t-1): s=1 activations + write
#pragma unroll
        for (int j = 0; j < 4; ++j) {
          float h = lstm_h(AC[4 + 0][j], AC[4 + 1][j], AC[4 + 2][j], AC[4 + 3][j],
                           BI[4], BI[5], BI[6], BI[7], CS[4 + j]);
          h2s[rb][4 * lg + j][32 * gw + 16 + l15] = (__bf16)h;
        }
      }
    }
    __syncthreads();  // B2: h1(t), h2(t-1) visible
  }

  // ---- final FC: out = h2(511) @ Wfc^T + bfc;  h2(511) is in buffer 1 ----
  if (tid < 160) {
    const int r = tid / 10, o = tid - r * 10;
    float sum = bfc[o];
    for (int u = 0; u < 128; ++u) sum += bf2f(h2s[1][r][u]) * Wfc[o * 128 + u];
    out[(size_t)(r0 + r) * 10 + o] = sum;
  }
}

extern "C" void kernel_launch(void* const* d_in, const int* in_sizes, int n_in,
                              void* d_out, int out_size, void* d_ws, size_t ws_size,
                              hipStream_t stream) {
  const float* x    = (const float*)d_in[0];
  const float* Wih0 = (const float*)d_in[1];
  const float* Whh0 = (const float*)d_in[2];
  const float* bih0 = (const float*)d_in[3];
  const float* bhh0 = (const float*)d_in[4];
  const float* Wih1 = (const float*)d_in[5];
  const float* Whh1 = (const float*)d_in[6];
  const float* bih1 = (const float*)d_in[7];
  const float* bhh1 = (const float*)d_in[8];
  const float* Wih2 = (const float*)d_in[9];
  const float* Whh2 = (const float*)d_in[10];
  const float* bih2 = (const float*)d_in[11];
  const float* bhh2 = (const float*)d_in[12];
  const float* Wfc  = (const float*)d_in[13];
  const float* bfc  = (const float*)d_in[14];

  lstm_kernel<<<256, 512, 0, stream>>>(x, Wih0, Whh0, bih0, bhh0,
                                       Wih1, Whh1, bih1, bhh1,
                                       Wih2, Whh2, bih2, bhh2,
                                       Wfc, bfc, (float*)d_out);
}

// Round 16
// 855.133 us; speedup vs baseline: 1.3195x; 1.0632x over previous
//
#include <hip/hip_runtime.h>

// B=4096, T=512, IN=32, H=[64,64,128], OUT=10
// 256 blocks x 512 threads (8 waves, 2/SIMD). ONE barrier/step via pipeline skew:
//   iteration t: G01 (waves 0-3): layer0(t) ; layer1(t-1)   [independent chains]
//                G23 (waves 4-7): layer2(t-2)
//                __syncthreads()
// Skew shifts WHEN each cell is computed, not WHAT: values identical to R13/R15.
// Race audit (h(t) stored in buffer t&1; pb=t&1, rb=pb^1):
//   l0 w:h0s[pb]=h0(t)    r:h0s[rb]=h0(t-1)                  (opposite buffer)
//   l1 w:h1s[rb]=h1(t-1)  r:h0s[rb]=h0(t-1) (same data l0 reads -> frag reuse),
//                         r:h1s[pb]=h1(t-2)                  (opposite buffer)
//   l2 w:h2s[pb]=h2(t-2)  r:h1s[pb]=h1(t-2) (prev iter, barrier-crossed),
//                         r:h2s[rb]=h2(t-3)                  (opposite buffer)
// Weights in AGPRs (PIN_A union AG[32] = 128 AGPR/wave; R11): G01 28 slots
// (Wih0/Whh0/Wih1/Whh1), G23 32 (Whh2); Wih2 from LDS. 512-thr keeps the
// 128-arch-VGPR budget with ZERO in-loop spills (R14's 1024-thr version spilled).
// 7-trans cell math (R15), pre-scaled biases (R12), native bf16 casts, builtin MFMAs.

using f32x4  = __attribute__((ext_vector_type(4))) float;
using bf16x8 = __attribute__((ext_vector_type(8))) __bf16;

#define KS (-1.442695041f)   // -log2(e)
#define KT (-2.885390082f)   // -2*log2(e)

__device__ __forceinline__ float bf2f(__bf16 b) {
  unsigned short s = __builtin_bit_cast(unsigned short, b);
  unsigned u = ((unsigned)s) << 16;
  return __builtin_bit_cast(float, u);
}

// LSTM cell pointwise math, 7 trans ops (5 exp2 + 2 rcp).  bi*: PRE-SCALED biases.
__device__ __forceinline__ float lstm_h(float ai, float af, float ag, float ao,
                                        float bi0, float bi1, float bi2, float bi3,
                                        float& cs) {
  float Ei = __builtin_amdgcn_exp2f(fmaf(KS, ai, bi0));
  float Ef = __builtin_amdgcn_exp2f(fmaf(KS, af, bi1));
  float Eg = __builtin_amdgcn_exp2f(fmaf(KT, ag, bi2));
  float Eo = __builtin_amdgcn_exp2f(fmaf(KS, ao, bi3));
  float Pi = 1.0f + Ei, Pf = 1.0f + Ef, Pg = 1.0f + Eg, Po = 1.0f + Eo;
  float PiPg = Pi * Pg;
  float N    = fmaf(Pf, 1.0f - Eg, cs * PiPg);
  float nc   = N * __builtin_amdgcn_rcpf(Pf * PiPg);
  cs = nc;
  float En = __builtin_amdgcn_exp2f(KT * nc);
  return (1.0f - En) * __builtin_amdgcn_rcpf(fmaf(Po, En, Po));  // (1-En)/(Po(1+En))
}

#define MF(A, Bv, C) __builtin_amdgcn_mfma_f32_16x16x32_bf16((A), (Bv), (C), 0, 0, 0)
#define PIN_A(v) asm volatile("" : "+a"(v))

__device__ __forceinline__ bf16x8 ldw8(const float* p) {
  float4 v0 = *(const float4*)p;
  float4 v1 = *(const float4*)(p + 4);
  bf16x8 r;
  r[0] = (__bf16)v0.x; r[1] = (__bf16)v0.y; r[2] = (__bf16)v0.z; r[3] = (__bf16)v0.w;
  r[4] = (__bf16)v1.x; r[5] = (__bf16)v1.y; r[6] = (__bf16)v1.z; r[7] = (__bf16)v1.w;
  return r;
}

__global__ __launch_bounds__(512)
void lstm_kernel(const float* __restrict__ x,
                 const float* __restrict__ Wih0, const float* __restrict__ Whh0,
                 const float* __restrict__ bih0, const float* __restrict__ bhh0,
                 const float* __restrict__ Wih1, const float* __restrict__ Whh1,
                 const float* __restrict__ bih1, const float* __restrict__ bhh1,
                 const float* __restrict__ Wih2, const float* __restrict__ Whh2,
                 const float* __restrict__ bih2, const float* __restrict__ bhh2,
                 const float* __restrict__ Wfc, const float* __restrict__ bfc,
                 float* __restrict__ out) {
  __shared__ __align__(16) __bf16 h0s[2][16][72];
  __shared__ __align__(16) __bf16 h1s[2][16][72];
  __shared__ __align__(16) __bf16 h2s[2][16][136];
  __shared__ __align__(16) __bf16 wih2l[512][72];

  const int tid = threadIdx.x;
  const int w   = tid >> 6;      // wave 0..7
  const bool g01 = (w < 4);
  const int gw  = w & 3;
  const int l   = tid & 63;
  const int l15 = l & 15;
  const int lg  = l >> 4;
  const int k0  = lg * 8;
  const int r0  = blockIdx.x << 4;

  for (int i = tid; i < 2 * 16 * 72; i += 512) {
    (&h0s[0][0][0])[i] = __bf16(0.f);
    (&h1s[0][0][0])[i] = __bf16(0.f);
  }
  for (int i = tid; i < 2 * 16 * 136; i += 512) (&h2s[0][0][0])[i] = __bf16(0.f);
  for (int i = tid; i < 512 * 64; i += 512) {
    int row = i >> 6, col = i & 63;
    wih2l[row][col] = (__bf16)Wih2[i];
  }

  // ---- SHARED weight array (union across roles), pinned to AGPRs ----
  // G01: AG[0..3]=Wih0, AG[4..11]=Whh0, AG[12..19]=Wih1, AG[20..27]=Whh1
  // G23: AG[0..31]=Whh2 (s,gi,kk -> 16s+4gi+kk)
  bf16x8 AG[32];
#pragma unroll
  for (int i = 0; i < 32; ++i) AG[i] = bf16x8{};
  f32x4  AC[8];     // G01: AC[0..3]=l0, AC[4..7]=l1; G23: AC[0..3]=s0, AC[4..7]=s1
  float  BI[8];     // pre-scaled biases (gi==2 -> KT*b else KS*b)
  float  CS[8];     // cell states
#pragma unroll
  for (int i = 0; i < 8; ++i) CS[i] = 0.f;

  if (g01) {
#pragma unroll
    for (int gi = 0; gi < 4; ++gi) {
      const int row = 16 * (4 * gi + gw) + l15;
      AG[gi] = ldw8(Wih0 + (size_t)row * 32 + k0);
#pragma unroll
      for (int kb = 0; kb < 2; ++kb) {
        AG[4 + 2 * gi + kb]  = ldw8(Whh0 + (size_t)row * 64 + kb * 32 + k0);
        AG[12 + 2 * gi + kb] = ldw8(Wih1 + (size_t)row * 64 + kb * 32 + k0);
        AG[20 + 2 * gi + kb] = ldw8(Whh1 + (size_t)row * 64 + kb * 32 + k0);
      }
      const float sc = (gi == 2) ? KT : KS;
      const int c01 = 64 * gi + 16 * gw + l15;
      BI[gi]     = sc * (bih0[c01] + bhh0[c01]);
      BI[4 + gi] = sc * (bih1[c01] + bhh1[c01]);
    }
  } else {
#pragma unroll
    for (int s = 0; s < 2; ++s)
#pragma unroll
      for (int gi = 0; gi < 4; ++gi) {
        const int row = 16 * (8 * gi + 2 * gw + s) + l15;
#pragma unroll
        for (int kk = 0; kk < 4; ++kk)
          AG[16 * s + 4 * gi + kk] = ldw8(Whh2 + (size_t)row * 128 + kk * 32 + k0);
        const float sc = (gi == 2) ? KT : KS;
        const int c2 = 128 * gi + 32 * gw + 16 * s + l15;
        BI[4 * s + gi] = sc * (bih2[c2] + bhh2[c2]);
      }
  }
#pragma unroll
  for (int i = 0; i < 32; ++i) PIN_A(AG[i]);

  const float* xrow = x + (size_t)(r0 + l15) * 512 * 32 + k0;
  float4 nx0 = {0.f, 0.f, 0.f, 0.f}, nx1 = {0.f, 0.f, 0.f, 0.f};
  if (g01) { nx0 = *(const float4*)xrow; nx1 = *(const float4*)(xrow + 4); }

  const f32x4 Z0 = {0.f, 0.f, 0.f, 0.f};

  __syncthreads();

#pragma unroll 1
  for (int t = 0; t <= 513; ++t) {
    const int pb = t & 1, rb = pb ^ 1;

    if (g01) {
      if (t <= 512) {
        // h0(t-1) fragments — shared input of l0(t) and l1(t-1)
        bf16x8 a0 = *(const bf16x8*)&h0s[rb][l15][k0];
        bf16x8 a1 = *(const bf16x8*)&h0s[rb][l15][32 + k0];

        if (t < 512) {
          // -------- layer0(t): h0(t) = cell(x(t), h0(t-1)) --------
          float4 cx0 = nx0, cx1 = nx1;
          const int tn = (t + 1) & 511;  // wraparound dummy at t=511
          nx0 = *(const float4*)(xrow + (size_t)tn * 32);
          nx1 = *(const float4*)(xrow + (size_t)tn * 32 + 4);

          bf16x8 ax;
          ax[0] = (__bf16)cx0.x; ax[1] = (__bf16)cx0.y; ax[2] = (__bf16)cx0.z; ax[3] = (__bf16)cx0.w;
          ax[4] = (__bf16)cx1.x; ax[5] = (__bf16)cx1.y; ax[6] = (__bf16)cx1.z; ax[7] = (__bf16)cx1.w;
#pragma unroll
          for (int gi = 0; gi < 4; ++gi) {
            f32x4 a = Z0;
            a = MF(ax, AG[gi], a);
            a = MF(a0, AG[4 + 2 * gi], a);
            a = MF(a1, AG[5 + 2 * gi], a);
            AC[gi] = a;
          }
#pragma unroll
          for (int j = 0; j < 4; ++j) {
            float h = lstm_h(AC[0][j], AC[1][j], AC[2][j], AC[3][j],
                             BI[0], BI[1], BI[2], BI[3], CS[j]);
            h0s[pb][4 * lg + j][16 * gw + l15] = (__bf16)h;
          }
        }

        if (t >= 1) {
          // -------- layer1(t-1): h1(t-1) = cell(h0(t-1), h1(t-2)) --------
          bf16x8 b0 = *(const bf16x8*)&h1s[pb][l15][k0];
          bf16x8 b1 = *(const bf16x8*)&h1s[pb][l15][32 + k0];
#pragma unroll
          for (int gi = 0; gi < 4; ++gi) {
            f32x4 a = Z0;
            a = MF(a0, AG[12 + 2 * gi], a);
            a = MF(a1, AG[13 + 2 * gi], a);
            a = MF(b0, AG[20 + 2 * gi], a);
            a = MF(b1, AG[21 + 2 * gi], a);
            AC[4 + gi] = a;
          }
#pragma unroll
          for (int j = 0; j < 4; ++j) {
            float h = lstm_h(AC[4][j], AC[5][j], AC[6][j], AC[7][j],
                             BI[4], BI[5], BI[6], BI[7], CS[4 + j]);
            h1s[rb][4 * lg + j][16 * gw + l15] = (__bf16)h;
          }
        }
      }
    } else {
      if (t >= 2) {
        // -------- layer2(t-2): h2(t-2) = cell(h1(t-2), h2(t-3)) --------
        bf16x8 b0 = *(const bf16x8*)&h1s[pb][l15][k0];
        bf16x8 b1 = *(const bf16x8*)&h1s[pb][l15][32 + k0];
        bf16x8 d0 = *(const bf16x8*)&h2s[rb][l15][k0];
        bf16x8 d1 = *(const bf16x8*)&h2s[rb][l15][32 + k0];
        bf16x8 d2 = *(const bf16x8*)&h2s[rb][l15][64 + k0];
        bf16x8 d3 = *(const bf16x8*)&h2s[rb][l15][96 + k0];
        // s = 0
#pragma unroll
        for (int gi = 0; gi < 4; ++gi) {
          const int tile = 8 * gi + 2 * gw;
          bf16x8 wa0 = *(const bf16x8*)&wih2l[16 * tile + l15][k0];
          bf16x8 wa1 = *(const bf16x8*)&wih2l[16 * tile + l15][32 + k0];
          f32x4 a = Z0;
          a = MF(b0, wa0, a);
          a = MF(b1, wa1, a);
          a = MF(d0, AG[4 * gi + 0], a);
          a = MF(d1, AG[4 * gi + 1], a);
          a = MF(d2, AG[4 * gi + 2], a);
          a = MF(d3, AG[4 * gi + 3], a);
          AC[gi] = a;
        }
#pragma unroll
        for (int j = 0; j < 4; ++j) {
          float h = lstm_h(AC[0][j], AC[1][j], AC[2][j], AC[3][j],
                           BI[0], BI[1], BI[2], BI[3], CS[j]);
          h2s[pb][4 * lg + j][32 * gw + l15] = (__bf16)h;
        }
        // s = 1
#pragma unroll
        for (int gi = 0; gi < 4; ++gi) {
          const int tile = 8 * gi + 2 * gw + 1;
          bf16x8 wa0 = *(const bf16x8*)&wih2l[16 * tile + l15][k0];
          bf16x8 wa1 = *(const bf16x8*)&wih2l[16 * tile + l15][32 + k0];
          f32x4 a = Z0;
          a = MF(b0, wa0, a);
          a = MF(b1, wa1, a);
          a = MF(d0, AG[16 + 4 * gi + 0], a);
          a = MF(d1, AG[16 + 4 * gi + 1], a);
          a = MF(d2, AG[16 + 4 * gi + 2], a);
          a = MF(d3, AG[16 + 4 * gi + 3], a);
          AC[4 + gi] = a;
        }
#pragma unroll
        for (int j = 0; j < 4; ++j) {
          float h = lstm_h(AC[4][j], AC[5][j], AC[6][j], AC[7][j],
                           BI[4], BI[5], BI[6], BI[7], CS[4 + j]);
          h2s[pb][4 * lg + j][32 * gw + 16 + l15] = (__bf16)h;
        }
      }
    }
    __syncthreads();  // single barrier per step
  }

  // ---- final FC: out = h2(511) @ Wfc^T + bfc;  h2(511) written at t=513 -> h2s[1]
  if (tid < 160) {
    const int r = tid / 10, o = tid - r * 10;
    float sum = bfc[o];
    for (int u = 0; u < 128; ++u) sum += bf2f(h2s[1][r][u]) * Wfc[o * 128 + u];
    out[(size_t)(r0 + r) * 10 + o] = sum;
  }
}

extern "C" void kernel_launch(void* const* d_in, const int* in_sizes, int n_in,
                              void* d_out, int out_size, void* d_ws, size_t ws_size,
                              hipStream_t stream) {
  const float* x    = (const float*)d_in[0];
  const float* Wih0 = (const float*)d_in[1];
  const float* Whh0 = (const float*)d_in[2];
  const float* bih0 = (const float*)d_in[3];
  const float* bhh0 = (const float*)d_in[4];
  const float* Wih1 = (const float*)d_in[5];
  const float* Whh1 = (const float*)d_in[6];
  const float* bih1 = (const float*)d_in[7];
  const float* bhh1 = (const float*)d_in[8];
  const float* Wih2 = (const float*)d_in[9];
  const float* Whh2 = (const float*)d_in[10];
  const float* bih2 = (const float*)d_in[11];
  const float* bhh2 = (const float*)d_in[12];
  const float* Wfc  = (const float*)d_in[13];
  const float* bfc  = (const float*)d_in[14];

  lstm_kernel<<<256, 512, 0, stream>>>(x, Wih0, Whh0, bih0, bhh0,
                                       Wih1, Whh1, bih1, bhh1,
                                       Wih2, Whh2, bih2, bhh2,
                                       Wfc, bfc, (float*)d_out);
}